// Round 8
// baseline (349.764 us; speedup 1.0000x reference)
//
#include <hip/hip_runtime.h>
#include <stdint.h>

typedef unsigned long long u64;
typedef unsigned int uint;

#define NB   2048   // batch
#define NF   8      // frames
#define NT   8      // LIF timesteps
#define NS   128    // state dim
#define NH   512    // hidden
#define NAct 4      // action dim
#define HEAD_B 8    // batches per head block
#define TPB  512    // k_snn threads; thread owns column h = tid (1 col/thread)
#define LW   516    // spike list row width (padded to multiple of 4)

// ---------------------------------------------------------------------------
// k_prep: Wt1d/Wt2d[k][h] = (double)W_h1[h][k] / (double)W_i2[h][k] with a
// zero row at k=NH (pad target; +0.0 is exact). fp32->fp64 cvt here is EXACT
// and identical to converting at the accumulate, so the gather sums are
// bit-identical to round 7 — but the per-event v_cvt_f64_f32 disappears.
// Wti1s[s][h] f32 (cvt amortized over 8 fma there); Wtf1[j][h] f32 head.
// ---------------------------------------------------------------------------
__global__ void k_prep(const float* __restrict__ W_i1,
                       const float* __restrict__ W_h1,
                       const float* __restrict__ W_i2,
                       const float* __restrict__ W_f1,
                       float* __restrict__ Wti1s,
                       double* __restrict__ Wt1d,
                       double* __restrict__ Wt2d,
                       float* __restrict__ Wtf1)
{
    int idx = blockIdx.x * 256 + threadIdx.x;
    if (idx < NS * NH) {                  // [s][h]
        int s = idx >> 9, h = idx & 511;
        Wti1s[idx] = W_i1[h * NS + s];
    }
    if (idx < NH * NH) {                  // [k][h]
        int k = idx >> 9, h = idx & 511;
        Wt1d[idx] = (double)W_h1[h * NH + k];
        Wt2d[idx] = (double)W_i2[h * NH + k];
    }
    if (idx < NH) {                       // zero row k = NH
        Wt1d[NH * NH + idx] = 0.0;
        Wt2d[NH * NH + idx] = 0.0;
    }
    if (idx < (NH + NAct) * NH) {         // [j][h]
        int j = idx / NH, hh = idx % NH;
        Wtf1[idx] = W_f1[hh * (NH + NAct) + j];
    }
}

// ---------------------------------------------------------------------------
// extraction, wave-parallel: wave t's lanes 0..7 turn timestep t's spike
// masks into a BYTE-OFFSET list (ascending k, offset = k*4096 = fp64 row
// stride), padded to x4 with the zero row's offset. Shift happens once per
// spike here instead of once per spike per wave in the gather.
// ---------------------------------------------------------------------------
__device__ __forceinline__ void extract_lists(int lane, int t,
                                              const u64 (*mask)[8],
                                              uint (*s_idx)[LW],
                                              uint* s_cnt)
{
    if (lane < 8) {
        const int w = lane;
        u64 m = mask[t][w];
        int base = 0;
        for (int w2 = 0; w2 < w; ++w2) base += (int)__popcll(mask[t][w2]);
        uint kbase = (uint)(w << 6);
        while (m) {
            int kb = __builtin_ctzll(m);
            m &= m - 1;
            s_idx[t][base++] = (kbase + (uint)kb) << 12;
        }
        if (w == 7) {
            uint cnt = (uint)base;
            uint pad = (4u - (cnt & 3u)) & 3u;
            for (uint p = 0; p < pad; ++p) s_idx[t][cnt + p] = (uint)NH << 12;
            s_cnt[t] = cnt + pad;
        }
    }
}

// ---------------------------------------------------------------------------
// gather4: sparse fp64 row-sum over a byte-offset list, 4-event chunks,
// double-buffered (issue chunk c+1 while consuming chunk c). Adds are
// strictly ascending-k fp64 -> bit-identical to the verified kernels.
// Row offset is wave-uniform (readfirstlane -> SGPR); payload load is
// saddr + tid*8 -> fully coalesced 512 B per wave.
// ---------------------------------------------------------------------------
#define LOAD4(P0,P1,P2,P3, base)                                  \
    {                                                             \
        uint4 qv = *(const uint4*)(lst + (base));                 \
        uint o0 = __builtin_amdgcn_readfirstlane(qv.x);           \
        uint o1 = __builtin_amdgcn_readfirstlane(qv.y);           \
        uint o2 = __builtin_amdgcn_readfirstlane(qv.z);           \
        uint o3 = __builtin_amdgcn_readfirstlane(qv.w);           \
        P0 = *(const double*)(tb + (o0 + hoff));                  \
        P1 = *(const double*)(tb + (o1 + hoff));                  \
        P2 = *(const double*)(tb + (o2 + hoff));                  \
        P3 = *(const double*)(tb + (o3 + hoff));                  \
    }

#define ADD4(P0,P1,P2,P3)  a += P0; a += P1; a += P2; a += P3;

__device__ __forceinline__ double gather4(const char* tb, const uint* lst,
                                          uint n, uint hoff)
{
    double a = 0.0;
    if (!n) return a;
    const uint m = n >> 2;                // chunks of 4 (n is a multiple of 4)
    double A0, A1, A2, A3, B0, B1, B2, B3;
    LOAD4(A0, A1, A2, A3, 0)
    uint c = 1;
    for (; c + 1 < m; c += 2) {
        LOAD4(B0, B1, B2, B3, c << 2)
        ADD4(A0, A1, A2, A3)
        LOAD4(A0, A1, A2, A3, (c + 1) << 2)
        ADD4(B0, B1, B2, B3)
    }
    if (c < m) {
        LOAD4(B0, B1, B2, B3, c << 2)
        ADD4(A0, A1, A2, A3)
        ADD4(B0, B1, B2, B3)
    } else {
        ADD4(A0, A1, A2, A3)
    }
    return a;
}

// ---------------------------------------------------------------------------
// k_snn: one block per batch, 8 waves, 1 column per thread. ih GEMV (fp64
// from exact fp32 weights), 8 frames of RNN1 (pipelined fp64 sparse gather +
// in-register LIF, double-buffered masks), RNN2 frame 7 (h2 == 0 provably:
// |x2| <= 22.7 << 999). Spike-path math fp64, values and add order
// op-for-op identical to the verified round-2..7 kernels.
// NOTE: no min-waves launch-bounds arg (round 4: forcing 8 waves/EU caps
// VGPR at 32 -> 345 MB/dispatch scratch spill, 4.3x slower).
// ---------------------------------------------------------------------------
__global__ __launch_bounds__(TPB) void k_snn(
    const float* __restrict__ state,    // [NB][NF][NS]
    const float* __restrict__ Wti1s,    // [NS][NH]
    const float* __restrict__ b_i1,
    const double* __restrict__ Wt1d,    // [NH+1][NH] fp64
    const float* __restrict__ b_h1,
    const double* __restrict__ Wt2d,    // [NH+1][NH] fp64
    const float* __restrict__ b_i2,
    const float* __restrict__ b_h2,
    float* __restrict__ vlast)          // [NB][NH] fp32
{
    const int b    = blockIdx.x;
    const int tid  = threadIdx.x;
    const int lane = tid & 63;
    const int wv   = tid >> 6;

    __shared__ double s_state[NF * NS];            // 8 KB, [f][s]
    __shared__ alignas(16) uint s_idx[NT][LW];     // 16.1 KB byte offsets
    __shared__ u64  s_mask[2][NT][8];              // 1 KB, double buffered
    __shared__ uint s_cnt[NT];

    // stage state (fp32 -> fp64, exact); 512 threads x float2 covers 1024
    {
        const float2* sp2 = (const float2*)(state + (size_t)b * NF * NS);
        float2 v2 = sp2[tid];
        s_state[tid * 2 + 0] = (double)v2.x;
        s_state[tid * 2 + 1] = (double)v2.y;
    }
    if (tid < 128) ((u64*)s_mask)[tid] = 0ull;     // frame 0 sees zero spikes
    __syncthreads();

    // ---- ih[f] for this thread's column, fp64, s-ascending fma ----
    double ih0[NF];
#pragma unroll
    for (int f = 0; f < NF; ++f) ih0[f] = 0.0;
    for (int s = 0; s < NS; ++s) {
        double w = (double)Wti1s[s * NH + tid];    // exact cvt
#pragma unroll
        for (int f = 0; f < NF; ++f)
            ih0[f] = fma(s_state[f * NS + s], w, ih0[f]);
    }
    {
        double bb = (double)b_i1[tid];
#pragma unroll
        for (int f = 0; f < NF; ++f) ih0[f] += bb;
    }
    const double bh1v = (double)b_h1[tid];
    const char*  w1b  = (const char*)Wt1d;
    const uint   hoff = (uint)tid * 8u;            // fp64 row stride = 4096 B

    // ---- 8 frames of RNN1 ----
    for (int f = 0; f < NF; ++f) {
        const int rb = f & 1, wb = rb ^ 1;
        __syncthreads();                           // prev masks final / lists consumed
        extract_lists(lane, wv, s_mask[rb], s_idx, s_cnt);
        __syncthreads();

        const double ihc = ih0[0];
        double v = 0.0;
        for (int t = 0; t < NT; ++t) {
            double a = gather4(w1b, s_idx[t], s_cnt[t], hoff);
            double x = (ihc + a) + bh1v;           // (ih + mm) + b, as reference
            v = v + (x - v) * 0.5;                 // v += (x - v)/TAU
            bool sp = (v - 1.0) >= 0.0;
            u64 m = __ballot(sp);
            if (lane == 0) s_mask[wb][t][wv] = m;
            if (sp) v = 0.0;                       // hard reset
        }
#pragma unroll
        for (int j = 0; j < NF - 1; ++j) ih0[j] = ih0[j + 1];
    }

    // ---- RNN2, frame 7 only; frame 7 wrote its spikes into buffer 0 ----
    __syncthreads();
    extract_lists(lane, wv, s_mask[0], s_idx, s_cnt);
    __syncthreads();

    {
        const char* w2b = (const char*)Wt2d;
        const double bi = (double)b_i2[tid];
        const double bg = (double)b_h2[tid];
        double v = 0.0;
        for (int t = 0; t < NT; ++t) {
            double a = gather4(w2b, s_idx[t], s_cnt[t], hoff);
            double x = (a + bi) + bg;              // ((mm + b_i2) + 0) + b_h2
            v = v + (x - v) * 0.5;
            if ((v - 999.0) >= 0.0) v = 0.0;       // faithful; never fires here
        }
        vlast[(size_t)b * NH + tid] = (float)v;
    }
}

// ---------------------------------------------------------------------------
// k_head: q = relu([v_last, action] @ W_f1.T + b_f1) @ W_f2.T + b_f2   (fp32)
// ---------------------------------------------------------------------------
__global__ __launch_bounds__(512) void k_head(
    const float* __restrict__ vlast,
    const float* __restrict__ action,
    const float* __restrict__ Wtf1,    // [516][512]
    const float* __restrict__ b_f1,
    const float* __restrict__ W_f2,
    const float* __restrict__ b_f2,
    float* __restrict__ q)
{
    const int h    = threadIdx.x;
    const int lane = h & 63;
    const int wv   = h >> 6;
    const int b0   = blockIdx.x * HEAD_B;

    __shared__ float s_x[HEAD_B][NH + NAct];
    for (int i = h; i < HEAD_B * NH; i += 512) {
        int bi = i / NH, j = i % NH;
        s_x[bi][j] = vlast[(size_t)(b0 + bi) * NH + j];
    }
    if (h < HEAD_B * NAct) {
        int bi = h / NAct, j = h % NAct;
        s_x[bi][NH + j] = action[(b0 + bi) * NAct + j];
    }
    __syncthreads();

    float acc[HEAD_B] = {0, 0, 0, 0, 0, 0, 0, 0};
#pragma unroll 4
    for (int j = 0; j < NH + NAct; ++j) {
        float w = Wtf1[j * NH + h];
#pragma unroll
        for (int i = 0; i < HEAD_B; ++i)
            acc[i] = fmaf(s_x[i][j], w, acc[i]);
    }

    const float bf = b_f1[h];
    const float w2 = W_f2[h];
    float p[HEAD_B];
#pragma unroll
    for (int i = 0; i < HEAD_B; ++i) {
        float hv = acc[i] + bf;
        hv = hv < 0.f ? 0.f : hv;
        p[i] = hv * w2;
    }
#pragma unroll
    for (int off = 32; off; off >>= 1) {
#pragma unroll
        for (int i = 0; i < HEAD_B; ++i)
            p[i] += __shfl_down(p[i], off);
    }
    __shared__ float red[8][HEAD_B];
    if (lane == 0) {
#pragma unroll
        for (int i = 0; i < HEAD_B; ++i) red[wv][i] = p[i];
    }
    __syncthreads();
    if (h < HEAD_B) {
        float s = 0.f;
#pragma unroll
        for (int w = 0; w < 8; ++w) s += red[w][h];
        q[b0 + h] = s + b_f2[0];
    }
}

// ---------------------------------------------------------------------------
extern "C" void kernel_launch(void* const* d_in, const int* in_sizes, int n_in,
                              void* d_out, int out_size, void* d_ws, size_t ws_size,
                              hipStream_t stream)
{
    const float* state  = (const float*)d_in[0];
    const float* action = (const float*)d_in[1];
    const float* W_i1   = (const float*)d_in[2];
    const float* b_i1   = (const float*)d_in[3];
    const float* W_h1   = (const float*)d_in[4];
    const float* b_h1   = (const float*)d_in[5];
    const float* W_i2   = (const float*)d_in[6];
    const float* b_i2   = (const float*)d_in[7];
    // d_in[8] = W_h2: provably unused (h2 spikes are identically zero)
    const float* b_h2   = (const float*)d_in[9];
    const float* W_f1   = (const float*)d_in[10];
    const float* b_f1   = (const float*)d_in[11];
    const float* W_f2   = (const float*)d_in[12];
    const float* b_f2   = (const float*)d_in[13];

    char* ws = (char*)d_ws;
    float*  Wti1s = (float*)(ws);                   // 128*512*4 = 262144 B
    double* Wt1d  = (double*)(ws + 262144);         // 513*512*8 = 2101248 B
    double* Wt2d  = (double*)(ws + 2363392);        // 513*512*8 = 2101248 B
    float*  Wtf1  = (float*)(ws + 4464640);         // 516*512*4 = 1056768 B
    float*  vlast = (float*)(ws + 5521408);         // 2048*512*4 = 4 MB

    k_prep<<<((NH + NAct) * NH + 255) / 256, 256, 0, stream>>>(
        W_i1, W_h1, W_i2, W_f1, Wti1s, Wt1d, Wt2d, Wtf1);

    k_snn<<<NB, TPB, 0, stream>>>(state, Wti1s, b_i1, Wt1d, b_h1,
                                  Wt2d, b_i2, b_h2, vlast);

    k_head<<<NB / HEAD_B, 512, 0, stream>>>(vlast, action, Wtf1, b_f1,
                                            W_f2, b_f2, (float*)d_out);
}

// Round 9
// 336.753 us; speedup vs baseline: 1.0386x; 1.0386x over previous
//
#include <hip/hip_runtime.h>
#include <stdint.h>

typedef unsigned long long u64;
typedef unsigned int uint;

#define NB   2048   // batch
#define NF   8      // frames
#define NT   8      // LIF timesteps
#define NS   128    // state dim
#define NH   512    // hidden
#define NAct 4      // action dim
#define HEAD_B 8    // batches per head block
#define TPB  512    // k_snn threads; thread owns column h = tid (1 col/thread)
#define LW   516    // spike list row width (padded to multiple of 4)

// ---------------------------------------------------------------------------
// k_prep: Wt1d[k][h] = (double)W_h1[h][k] — fp64 so the HOT gather (RNN1,
// 8 of 9 passes) skips the per-event v_cvt_f64_f32. Wt1d is 2.1 MB; together
// with state/lists it stays under the 4 MiB per-XCD L2 (round 8 lesson:
// BOTH tables in fp64 = 4.2 MB -> L2 thrash, FETCH 36 MB, 1.7x slower).
// Wt2s[k][h] stays fp32 (cvt paid once, in the single RNN2 pass). Zero row
// at k=NH pads lists (+0.0 exact). fp32->fp64 cvt is EXACT, so all sums are
// bit-identical to the verified round-2..7 kernels.
// ---------------------------------------------------------------------------
__global__ void k_prep(const float* __restrict__ W_i1,
                       const float* __restrict__ W_h1,
                       const float* __restrict__ W_i2,
                       const float* __restrict__ W_f1,
                       float* __restrict__ Wti1s,
                       double* __restrict__ Wt1d,
                       float* __restrict__ Wt2s,
                       float* __restrict__ Wtf1)
{
    int idx = blockIdx.x * 256 + threadIdx.x;
    if (idx < NS * NH) {                  // [s][h]
        int s = idx >> 9, h = idx & 511;
        Wti1s[idx] = W_i1[h * NS + s];
    }
    if (idx < NH * NH) {                  // [k][h]
        int k = idx >> 9, h = idx & 511;
        Wt1d[idx] = (double)W_h1[h * NH + k];
        Wt2s[idx] = W_i2[h * NH + k];
    }
    if (idx < NH) {                       // zero row k = NH
        Wt1d[NH * NH + idx] = 0.0;
        Wt2s[NH * NH + idx] = 0.f;
    }
    if (idx < (NH + NAct) * NH) {         // [j][h]
        int j = idx / NH, hh = idx % NH;
        Wtf1[idx] = W_f1[hh * (NH + NAct) + j];
    }
}

// ---------------------------------------------------------------------------
// extraction, wave-parallel: wave t's lanes 0..7 turn timestep t's spike
// masks into a BYTE-OFFSET list for the fp64 table (ascending k, offset =
// k*4096), padded to x4 with the zero row. Shift once per spike here,
// not once per spike per wave in the gather. RNN2 derives its fp32-table
// offset via one SGPR shift (>>1) per event.
// ---------------------------------------------------------------------------
__device__ __forceinline__ void extract_lists(int lane, int t,
                                              const u64 (*mask)[8],
                                              uint (*s_idx)[LW],
                                              uint* s_cnt)
{
    if (lane < 8) {
        const int w = lane;
        u64 m = mask[t][w];
        int base = 0;
        for (int w2 = 0; w2 < w; ++w2) base += (int)__popcll(mask[t][w2]);
        uint kbase = (uint)(w << 6);
        while (m) {
            int kb = __builtin_ctzll(m);
            m &= m - 1;
            s_idx[t][base++] = (kbase + (uint)kb) << 12;
        }
        if (w == 7) {
            uint cnt = (uint)base;
            uint pad = (4u - (cnt & 3u)) & 3u;
            for (uint p = 0; p < pad; ++p) s_idx[t][cnt + p] = (uint)NH << 12;
            s_cnt[t] = cnt + pad;
        }
    }
}

// ---------------------------------------------------------------------------
// gather4_d: fp64-table sparse row-sum, 4-event chunks, double-buffered.
// No per-event cvt. Row offset wave-uniform (readfirstlane -> SGPR);
// payload load saddr + tid*8 -> coalesced 512 B per wave (L2-resident).
// Adds strictly ascending-k fp64 -> bit-identical to verified kernels.
// ---------------------------------------------------------------------------
#define LOAD4D(P0,P1,P2,P3, base)                                 \
    {                                                             \
        uint4 qv = *(const uint4*)(lst + (base));                 \
        uint o0 = __builtin_amdgcn_readfirstlane(qv.x);           \
        uint o1 = __builtin_amdgcn_readfirstlane(qv.y);           \
        uint o2 = __builtin_amdgcn_readfirstlane(qv.z);           \
        uint o3 = __builtin_amdgcn_readfirstlane(qv.w);           \
        P0 = *(const double*)(tb + (o0 + hoff));                  \
        P1 = *(const double*)(tb + (o1 + hoff));                  \
        P2 = *(const double*)(tb + (o2 + hoff));                  \
        P3 = *(const double*)(tb + (o3 + hoff));                  \
    }

#define ADD4D(P0,P1,P2,P3)  a += P0; a += P1; a += P2; a += P3;

__device__ __forceinline__ double gather4_d(const char* tb, const uint* lst,
                                            uint n, uint hoff)
{
    double a = 0.0;
    if (!n) return a;
    const uint m = n >> 2;
    double A0, A1, A2, A3, B0, B1, B2, B3;
    LOAD4D(A0, A1, A2, A3, 0)
    uint c = 1;
    for (; c + 1 < m; c += 2) {
        LOAD4D(B0, B1, B2, B3, c << 2)
        ADD4D(A0, A1, A2, A3)
        LOAD4D(A0, A1, A2, A3, (c + 1) << 2)
        ADD4D(B0, B1, B2, B3)
    }
    if (c < m) {
        LOAD4D(B0, B1, B2, B3, c << 2)
        ADD4D(A0, A1, A2, A3)
        ADD4D(B0, B1, B2, B3)
    } else {
        ADD4D(A0, A1, A2, A3)
    }
    return a;
}

// ---------------------------------------------------------------------------
// gather4_s: fp32-table variant (RNN2 only — 1 of 9 passes). Offset is the
// fp64 byte offset >>1 (SGPR shift). Per-event cvt f32->f64 (exact).
// ---------------------------------------------------------------------------
#define LOAD4S(P0,P1,P2,P3, base)                                 \
    {                                                             \
        uint4 qv = *(const uint4*)(lst + (base));                 \
        uint o0 = __builtin_amdgcn_readfirstlane(qv.x) >> 1;      \
        uint o1 = __builtin_amdgcn_readfirstlane(qv.y) >> 1;      \
        uint o2 = __builtin_amdgcn_readfirstlane(qv.z) >> 1;      \
        uint o3 = __builtin_amdgcn_readfirstlane(qv.w) >> 1;      \
        P0 = *(const float*)(tb + (o0 + hoff));                   \
        P1 = *(const float*)(tb + (o1 + hoff));                   \
        P2 = *(const float*)(tb + (o2 + hoff));                   \
        P3 = *(const float*)(tb + (o3 + hoff));                   \
    }

#define ADD4S(P0,P1,P2,P3)                                        \
    a += (double)P0; a += (double)P1; a += (double)P2; a += (double)P3;

__device__ __forceinline__ double gather4_s(const char* tb, const uint* lst,
                                            uint n, uint hoff)
{
    double a = 0.0;
    if (!n) return a;
    const uint m = n >> 2;
    float A0, A1, A2, A3, B0, B1, B2, B3;
    LOAD4S(A0, A1, A2, A3, 0)
    uint c = 1;
    for (; c + 1 < m; c += 2) {
        LOAD4S(B0, B1, B2, B3, c << 2)
        ADD4S(A0, A1, A2, A3)
        LOAD4S(A0, A1, A2, A3, (c + 1) << 2)
        ADD4S(B0, B1, B2, B3)
    }
    if (c < m) {
        LOAD4S(B0, B1, B2, B3, c << 2)
        ADD4S(A0, A1, A2, A3)
        ADD4S(B0, B1, B2, B3)
    } else {
        ADD4S(A0, A1, A2, A3)
    }
    return a;
}

// ---------------------------------------------------------------------------
// k_snn: one block per batch, 8 waves, 1 column per thread. ih GEMV (fp64
// from exact fp32 weights), 8 frames of RNN1 (pipelined fp64 sparse gather +
// in-register LIF, double-buffered masks), RNN2 frame 7 (h2 == 0 provably:
// |x2| <= 22.7 << 999). Spike-path math fp64, values and add order
// op-for-op identical to the verified round-2..7 kernels.
// NOTE: no min-waves launch-bounds arg (round 4: forcing 8 waves/EU caps
// VGPR at 32 -> 345 MB/dispatch scratch spill, 4.3x slower).
// ---------------------------------------------------------------------------
__global__ __launch_bounds__(TPB) void k_snn(
    const float* __restrict__ state,    // [NB][NF][NS]
    const float* __restrict__ Wti1s,    // [NS][NH]
    const float* __restrict__ b_i1,
    const double* __restrict__ Wt1d,    // [NH+1][NH] fp64
    const float* __restrict__ b_h1,
    const float* __restrict__ Wt2s,     // [NH+1][NH] fp32
    const float* __restrict__ b_i2,
    const float* __restrict__ b_h2,
    float* __restrict__ vlast)          // [NB][NH] fp32
{
    const int b    = blockIdx.x;
    const int tid  = threadIdx.x;
    const int lane = tid & 63;
    const int wv   = tid >> 6;

    __shared__ double s_state[NF * NS];            // 8 KB, [f][s]
    __shared__ alignas(16) uint s_idx[NT][LW];     // 16.1 KB byte offsets
    __shared__ u64  s_mask[2][NT][8];              // 1 KB, double buffered
    __shared__ uint s_cnt[NT];

    // stage state (fp32 -> fp64, exact); 512 threads x float2 covers 1024
    {
        const float2* sp2 = (const float2*)(state + (size_t)b * NF * NS);
        float2 v2 = sp2[tid];
        s_state[tid * 2 + 0] = (double)v2.x;
        s_state[tid * 2 + 1] = (double)v2.y;
    }
    if (tid < 128) ((u64*)s_mask)[tid] = 0ull;     // frame 0 sees zero spikes
    __syncthreads();

    // ---- ih[f] for this thread's column, fp64, s-ascending fma ----
    double ih0[NF];
#pragma unroll
    for (int f = 0; f < NF; ++f) ih0[f] = 0.0;
    for (int s = 0; s < NS; ++s) {
        double w = (double)Wti1s[s * NH + tid];    // exact cvt
#pragma unroll
        for (int f = 0; f < NF; ++f)
            ih0[f] = fma(s_state[f * NS + s], w, ih0[f]);
    }
    {
        double bb = (double)b_i1[tid];
#pragma unroll
        for (int f = 0; f < NF; ++f) ih0[f] += bb;
    }
    const double bh1v = (double)b_h1[tid];
    const char*  w1b  = (const char*)Wt1d;
    const uint   hoff8 = (uint)tid * 8u;           // fp64 row: col offset
    const uint   hoff4 = (uint)tid * 4u;           // fp32 row: col offset

    // ---- 8 frames of RNN1 ----
    for (int f = 0; f < NF; ++f) {
        const int rb = f & 1, wb = rb ^ 1;
        __syncthreads();                           // prev masks final / lists consumed
        extract_lists(lane, wv, s_mask[rb], s_idx, s_cnt);
        __syncthreads();

        const double ihc = ih0[0];
        double v = 0.0;
        for (int t = 0; t < NT; ++t) {
            double a = gather4_d(w1b, s_idx[t], s_cnt[t], hoff8);
            double x = (ihc + a) + bh1v;           // (ih + mm) + b, as reference
            v = v + (x - v) * 0.5;                 // v += (x - v)/TAU
            bool sp = (v - 1.0) >= 0.0;
            u64 m = __ballot(sp);
            if (lane == 0) s_mask[wb][t][wv] = m;
            if (sp) v = 0.0;                       // hard reset
        }
#pragma unroll
        for (int j = 0; j < NF - 1; ++j) ih0[j] = ih0[j + 1];
    }

    // ---- RNN2, frame 7 only; frame 7 wrote its spikes into buffer 0 ----
    __syncthreads();
    extract_lists(lane, wv, s_mask[0], s_idx, s_cnt);
    __syncthreads();

    {
        const char* w2b = (const char*)Wt2s;
        const double bi = (double)b_i2[tid];
        const double bg = (double)b_h2[tid];
        double v = 0.0;
        for (int t = 0; t < NT; ++t) {
            double a = gather4_s(w2b, s_idx[t], s_cnt[t], hoff4);
            double x = (a + bi) + bg;              // ((mm + b_i2) + 0) + b_h2
            v = v + (x - v) * 0.5;
            if ((v - 999.0) >= 0.0) v = 0.0;       // faithful; never fires here
        }
        vlast[(size_t)b * NH + tid] = (float)v;
    }
}

// ---------------------------------------------------------------------------
// k_head: q = relu([v_last, action] @ W_f1.T + b_f1) @ W_f2.T + b_f2   (fp32)
// ---------------------------------------------------------------------------
__global__ __launch_bounds__(512) void k_head(
    const float* __restrict__ vlast,
    const float* __restrict__ action,
    const float* __restrict__ Wtf1,    // [516][512]
    const float* __restrict__ b_f1,
    const float* __restrict__ W_f2,
    const float* __restrict__ b_f2,
    float* __restrict__ q)
{
    const int h    = threadIdx.x;
    const int lane = h & 63;
    const int wv   = h >> 6;
    const int b0   = blockIdx.x * HEAD_B;

    __shared__ float s_x[HEAD_B][NH + NAct];
    for (int i = h; i < HEAD_B * NH; i += 512) {
        int bi = i / NH, j = i % NH;
        s_x[bi][j] = vlast[(size_t)(b0 + bi) * NH + j];
    }
    if (h < HEAD_B * NAct) {
        int bi = h / NAct, j = h % NAct;
        s_x[bi][NH + j] = action[(b0 + bi) * NAct + j];
    }
    __syncthreads();

    float acc[HEAD_B] = {0, 0, 0, 0, 0, 0, 0, 0};
#pragma unroll 4
    for (int j = 0; j < NH + NAct; ++j) {
        float w = Wtf1[j * NH + h];
#pragma unroll
        for (int i = 0; i < HEAD_B; ++i)
            acc[i] = fmaf(s_x[i][j], w, acc[i]);
    }

    const float bf = b_f1[h];
    const float w2 = W_f2[h];
    float p[HEAD_B];
#pragma unroll
    for (int i = 0; i < HEAD_B; ++i) {
        float hv = acc[i] + bf;
        hv = hv < 0.f ? 0.f : hv;
        p[i] = hv * w2;
    }
#pragma unroll
    for (int off = 32; off; off >>= 1) {
#pragma unroll
        for (int i = 0; i < HEAD_B; ++i)
            p[i] += __shfl_down(p[i], off);
    }
    __shared__ float red[8][HEAD_B];
    if (lane == 0) {
#pragma unroll
        for (int i = 0; i < HEAD_B; ++i) red[wv][i] = p[i];
    }
    __syncthreads();
    if (h < HEAD_B) {
        float s = 0.f;
#pragma unroll
        for (int w = 0; w < 8; ++w) s += red[w][h];
        q[b0 + h] = s + b_f2[0];
    }
}

// ---------------------------------------------------------------------------
extern "C" void kernel_launch(void* const* d_in, const int* in_sizes, int n_in,
                              void* d_out, int out_size, void* d_ws, size_t ws_size,
                              hipStream_t stream)
{
    const float* state  = (const float*)d_in[0];
    const float* action = (const float*)d_in[1];
    const float* W_i1   = (const float*)d_in[2];
    const float* b_i1   = (const float*)d_in[3];
    const float* W_h1   = (const float*)d_in[4];
    const float* b_h1   = (const float*)d_in[5];
    const float* W_i2   = (const float*)d_in[6];
    const float* b_i2   = (const float*)d_in[7];
    // d_in[8] = W_h2: provably unused (h2 spikes are identically zero)
    const float* b_h2   = (const float*)d_in[9];
    const float* W_f1   = (const float*)d_in[10];
    const float* b_f1   = (const float*)d_in[11];
    const float* W_f2   = (const float*)d_in[12];
    const float* b_f2   = (const float*)d_in[13];

    char* ws = (char*)d_ws;
    float*  Wti1s = (float*)(ws);                   // 128*512*4 = 262144 B
    double* Wt1d  = (double*)(ws + 262144);         // 513*512*8 = 2101248 B
    float*  Wt2s  = (float*)(ws + 2363392);         // 513*512*4 = 1050624 B
    float*  Wtf1  = (float*)(ws + 3414016);         // 516*512*4 = 1056768 B
    float*  vlast = (float*)(ws + 4470784);         // 2048*512*4 = 4 MB

    k_prep<<<((NH + NAct) * NH + 255) / 256, 256, 0, stream>>>(
        W_i1, W_h1, W_i2, W_f1, Wti1s, Wt1d, Wt2s, Wtf1);

    k_snn<<<NB, TPB, 0, stream>>>(state, Wti1s, b_i1, Wt1d, b_h1,
                                  Wt2s, b_i2, b_h2, vlast);

    k_head<<<NB / HEAD_B, 512, 0, stream>>>(vlast, action, Wtf1, b_f1,
                                            W_f2, b_f2, (float*)d_out);
}